// Round 3
// baseline (244.046 us; speedup 1.0000x reference)
//
#include <hip/hip_runtime.h>

#define K 7
#define KK 49
#define BLK 256
#define TPP 4                    // threads per pixel
#define PPB (BLK / TPP)          // 64 pixels per block
#define NW 13                    // ceil(49/4) weights per thread
#define CHUNK_F4 (PPB * KK / 4)  // 784 float4 per block

// Catmull-Rom a=-0.5, branchless truncated-power form:
// w = 0.5*t2^3 - 0.5*t2^2 + t1^2 - 2*t1^3,  t2=max(0,2-|x|), t1=max(0,1-|x|)
__device__ __forceinline__ float cubic_c(float x) {
    float ax = __builtin_fabsf(x);
    float t2 = __builtin_fmaxf(2.0f - ax, 0.0f);
    float t1 = __builtin_fmaxf(1.0f - ax, 0.0f);
    float r  = (t2 * t2) * __builtin_fmaf(0.5f, t2, -0.5f);
    return __builtin_fmaf(t1 * t1, __builtin_fmaf(-2.0f, t1, 1.0f), r);
}

__global__ __launch_bounds__(BLK, 8) void kest_kernel(
    const float* __restrict__ m,
    const float* __restrict__ grid,
    const int*   __restrict__ Wp,
    const int*   __restrict__ yi,
    float*       __restrict__ out,
    int N)
{
    __shared__ __align__(16) float lds[PPB * KK];   // 12544 B -> 8 blocks/CU

    const int tid  = threadIdx.x;
    const int sub  = tid & (TPP - 1);
    const int pixL = tid >> 2;
    const int i    = blockIdx.x * PPB + pixL;

    const float m00 = m[0], m01 = m[1], m02 = m[2];
    const float m10 = m[3], m11 = m[4], m12 = m[5];
    const float m20 = m[6], m21 = m[7], m22 = m[8];
    const int   W   = Wp[0];

    if (i < N) {
        const int j = yi[i];
        int yyI, xxI;
        if ((W & (W - 1)) == 0) {            // uniform branch; W=1024 in practice
            yyI = j >> (__ffs(W) - 1);
            xxI = j & (W - 1);
        } else {
            yyI = j / W;
            xxI = j - yyI * W;
        }
        const float xx = (float)xxI;
        const float yy = (float)yyI;

        const float X0 = m00 * xx + m01 * yy + m02;
        const float Y0 = m10 * xx + m11 * yy + m12;
        const float Z0 = m20 * xx + m21 * yy + m22;

        // stable difference-of-quotients: du (eps_y=±0.5), dv (eps_x=±0.5)
        const float izy = 1.0f / (Z0 * Z0 - 0.25f * m21 * m21);
        float du0 = (m01 * Z0 - m21 * X0) * izy;
        float du1 = (m11 * Z0 - m21 * Y0) * izy;
        const float izx = 1.0f / (Z0 * Z0 - 0.25f * m20 * m20);
        float dv0 = (m00 * Z0 - m20 * X0) * izx;
        float dv1 = (m10 * Z0 - m20 * Y0) * izx;

        float len_du = __builtin_sqrtf(du0 * du0 + du1 * du1);
        if (len_du < 1.0f) {
            float r = 1.0f / len_du;
            du0 *= r; du1 *= r;
            len_du = 1.0f;
        }
        float len_dv = __builtin_sqrtf(dv0 * dv0 + dv1 * dv1);
        if (len_dv < 1.0f) {
            float r = 1.0f / len_dv;
            dv0 *= r; dv1 *= r;
            len_dv = 1.0f;
        }

        const float det  = du0 * dv1 - du1 * dv0;
        const float r_du = 1.0f / (len_du * det);
        const float r_dv = 1.0f / (len_dv * det);

        // x = Axx*wxv + Axy*wyv ; y = Ayx*wxv + Ayy*wyv
        const float p1 = du0 * dv1, p2 = du1 * dv0;
        const float Axx = p1 * r_du - p2 * r_dv;
        const float Axy = du0 * du1 * (r_dv - r_du);
        const float Ayx = dv0 * dv1 * (r_du - r_dv);
        const float Ayy = p1 * r_dv - p2 * r_du;

        const float px  = grid[i]     + 0.5f;
        const float py  = grid[N + i] + 0.5f;
        const float fxc = (px - __builtin_floorf(px)) + 2.5f;
        const float fyc = (py - __builtin_floorf(py)) + 2.5f;

        // this thread computes weights q = 4*qq + sub, qq = 0..12
        float wv[NW];
        float wsum = 0.0f;
        int kx = sub, ky = 0;
#pragma unroll
        for (int qq = 0; qq < NW; ++qq) {
            const float wxv = fxc - (float)kx;
            const float wyv = fyc - (float)ky;
            const float x = __builtin_fmaf(Axx, wxv, Axy * wyv);
            const float y = __builtin_fmaf(Ayx, wxv, Ayy * wyv);
            float t = cubic_c(x) * cubic_c(y);
            if (qq == NW - 1 && sub >= 1) t = 0.0f;   // q = 48+sub > 48 invalid
            wv[qq] = t;
            wsum += t;
            kx += TPP;
            if (kx >= K) { kx -= K; ++ky; }           // step 4 < 7: single wrap
        }
        // combine partial sums across the 4 lanes of this pixel (contiguous lanes)
        wsum += __shfl_xor(wsum, 1);
        wsum += __shfl_xor(wsum, 2);
        const float rs = 1.0f / wsum;

        float* p = &lds[pixL * KK + sub];
#pragma unroll
        for (int qq = 0; qq < NW; ++qq) {
            if (qq < NW - 1 || sub == 0)               // skip invalid q >= 49
                p[4 * qq] = wv[qq] * rs;
        }
    }
    __syncthreads();

    // pure coalesced drain: 784 float4 per block
    const long long baseF4 = (long long)blockIdx.x * CHUNK_F4;
    const long long limF4  = ((long long)N * KK) >> 2;
    const float4* src = (const float4*)lds;
    float4*       dst = (float4*)out + baseF4;
#pragma unroll
    for (int k = 0; k < 4; ++k) {
        const int t = tid + k * BLK;
        if (t < CHUNK_F4 && baseF4 + t < limF4) dst[t] = src[t];
    }
}

extern "C" void kernel_launch(void* const* d_in, const int* in_sizes, int n_in,
                              void* d_out, int out_size, void* d_ws, size_t ws_size,
                              hipStream_t stream) {
    // inputs: m_inverse(9 f32), grid(2N f32), H(1 i32), W(1 i32), yi(N i32)
    const float* m    = (const float*)d_in[0];
    const float* grid = (const float*)d_in[1];
    const int*   Wp   = (const int*)d_in[3];
    const int*   yi   = (const int*)d_in[4];
    float*       out  = (float*)d_out;
    const int N = in_sizes[4];

    const int blocks = (N + PPB - 1) / PPB;
    kest_kernel<<<blocks, BLK, 0, stream>>>(m, grid, Wp, yi, out, N);
}

// Round 4
// 219.767 us; speedup vs baseline: 1.1105x; 1.1105x over previous
//
#include <hip/hip_runtime.h>

#define K 7
#define KK 49
#define BLK 256
#define TPP 2                    // threads per pixel
#define PPB (BLK / TPP)          // 128 pixels per block
#define NW 25                    // weights per thread (last valid only for sub=0)
#define CHUNK_F4 (PPB * KK / 4)  // 1568 float4 per block

// Catmull-Rom a=-0.5, branchless truncated-power form:
// w = 0.5*t2^3 - 0.5*t2^2 + t1^2 - 2*t1^3,  t2=max(0,2-|x|), t1=max(0,1-|x|)
__device__ __forceinline__ float cubic_c(float x) {
    float ax = __builtin_fabsf(x);
    float t2 = __builtin_fmaxf(2.0f - ax, 0.0f);
    float t1 = __builtin_fmaxf(1.0f - ax, 0.0f);
    float r  = (t2 * t2) * __builtin_fmaf(0.5f, t2, -0.5f);
    return __builtin_fmaf(t1 * t1, __builtin_fmaf(-2.0f, t1, 1.0f), r);
}

__global__ __launch_bounds__(BLK, 6) void kest_kernel(
    const float* __restrict__ m,
    const float* __restrict__ grid,
    const int*   __restrict__ Wp,
    const int*   __restrict__ yi,
    float*       __restrict__ out,
    int N)
{
    __shared__ __align__(16) float lds[PPB * KK];   // 25088 B -> 6 blocks/CU

    const int tid  = threadIdx.x;
    const int sub  = tid & (TPP - 1);
    const int pixL = tid >> 1;
    const int i    = blockIdx.x * PPB + pixL;

    if (i < N) {
        const float m00 = m[0], m01 = m[1], m02 = m[2];
        const float m10 = m[3], m11 = m[4], m12 = m[5];
        const float m20 = m[6], m21 = m[7], m22 = m[8];
        const int   W   = Wp[0];

        const int j = yi[i];
        int yyI, xxI;
        if ((W & (W - 1)) == 0) {            // uniform branch; W=1024 in practice
            yyI = j >> (__ffs(W) - 1);
            xxI = j & (W - 1);
        } else {
            yyI = j / W;
            xxI = j - yyI * W;
        }
        const float xx = (float)xxI;
        const float yy = (float)yyI;

        const float X0 = m00 * xx + m01 * yy + m02;
        const float Y0 = m10 * xx + m11 * yy + m12;
        const float Z0 = m20 * xx + m21 * yy + m22;

        // stable difference-of-quotients: du (eps_y=±0.5), dv (eps_x=±0.5)
        const float izy = __builtin_amdgcn_rcpf(Z0 * Z0 - 0.25f * m21 * m21);
        float du0 = (m01 * Z0 - m21 * X0) * izy;
        float du1 = (m11 * Z0 - m21 * Y0) * izy;
        const float izx = __builtin_amdgcn_rcpf(Z0 * Z0 - 0.25f * m20 * m20);
        float dv0 = (m00 * Z0 - m20 * X0) * izx;
        float dv1 = (m10 * Z0 - m20 * Y0) * izx;

        // regularize |du|>=1, |dv|>=1 via rsq (1-ulp ok: threshold 2e-2)
        const float d2u = du0 * du0 + du1 * du1;
        const float rlu = __builtin_amdgcn_rsqf(d2u);
        float len_du = d2u * rlu;                    // = sqrt(d2u)
        if (len_du < 1.0f) { du0 *= rlu; du1 *= rlu; len_du = 1.0f; }
        const float d2v = dv0 * dv0 + dv1 * dv1;
        const float rlv = __builtin_amdgcn_rsqf(d2v);
        float len_dv = d2v * rlv;
        if (len_dv < 1.0f) { dv0 *= rlv; dv1 *= rlv; len_dv = 1.0f; }

        const float det  = du0 * dv1 - du1 * dv0;
        const float r_du = __builtin_amdgcn_rcpf(len_du * det);
        const float r_dv = __builtin_amdgcn_rcpf(len_dv * det);

        // x = Axx*wxv + Axy*wyv ; y = Ayx*wxv + Ayy*wyv
        const float p1 = du0 * dv1, p2 = du1 * dv0;
        const float Axx = p1 * r_du - p2 * r_dv;
        const float Axy = du0 * du1 * (r_dv - r_du);
        const float Ayx = dv0 * dv1 * (r_du - r_dv);
        const float Ayy = p1 * r_dv - p2 * r_du;

        const float px  = grid[i]     + 0.5f;
        const float py  = grid[N + i] + 0.5f;
        const float fxc = (px - __builtin_floorf(px)) + 2.5f;
        const float fyc = (py - __builtin_floorf(py)) + 2.5f;
        const float subf = (float)sub;

        // this thread computes weights q = 2*qq + sub, qq = 0..24
        float wv[NW];
        float wsum = 0.0f;
#pragma unroll
        for (int qq = 0; qq < NW; ++qq) {
            // compile-time constants: c0=(2qq)%7, c1=(2qq+1)%7, r0,r1 = /7
            const int c0 = (2 * qq) % 7,  c1 = (2 * qq + 1) % 7;
            const int r0 = (2 * qq) / 7,  r1 = (2 * qq + 1) / 7;
            // wxv = fxc - (sub ? c1 : c0) = fma(subf, c0-c1, fxc-c0)
            const float wxv = __builtin_fmaf(subf, (float)(c0 - c1), fxc - (float)c0);
            const float wyv = __builtin_fmaf(subf, (float)(r0 - r1), fyc - (float)r0);
            const float x = __builtin_fmaf(Axx, wxv, Axy * wyv);
            const float y = __builtin_fmaf(Ayx, wxv, Ayy * wyv);
            float t = cubic_c(x) * cubic_c(y);
            if (qq == NW - 1) t = sub ? 0.0f : t;    // q = 49 invalid
            wv[qq] = t;
            wsum += t;
        }
        // combine the 2 partial sums of this pixel (adjacent lanes)
        wsum += __shfl_xor(wsum, 1);
        const float rs = __builtin_amdgcn_rcpf(wsum);

        // LDS write: addr = 49*pixL + sub + 2qq; banks 17*pixL mod 32 bijective
        // across a wave -> at most 2-way aliasing (free)
        float* p = &lds[pixL * KK + sub];
#pragma unroll
        for (int qq = 0; qq < NW; ++qq) {
            if (qq < NW - 1 || sub == 0)
                p[2 * qq] = wv[qq] * rs;
        }
    }
    __syncthreads();   // single barrier; no global stores outstanding yet

    // pure coalesced drain: 1568 float4 per block
    const long long baseF4 = (long long)blockIdx.x * CHUNK_F4;
    const long long limF4  = ((long long)N * KK) >> 2;
    const float4* src = (const float4*)lds;
    float4*       dst = (float4*)out + baseF4;
#pragma unroll
    for (int k = 0; k < 7; ++k) {
        const int t = tid + k * BLK;
        if (t < CHUNK_F4 && baseF4 + t < limF4) dst[t] = src[t];
    }
}

extern "C" void kernel_launch(void* const* d_in, const int* in_sizes, int n_in,
                              void* d_out, int out_size, void* d_ws, size_t ws_size,
                              hipStream_t stream) {
    // inputs: m_inverse(9 f32), grid(2N f32), H(1 i32), W(1 i32), yi(N i32)
    const float* m    = (const float*)d_in[0];
    const float* grid = (const float*)d_in[1];
    const int*   Wp   = (const int*)d_in[3];
    const int*   yi   = (const int*)d_in[4];
    float*       out  = (float*)d_out;
    const int N = in_sizes[4];

    const int blocks = (N + PPB - 1) / PPB;
    kest_kernel<<<blocks, BLK, 0, stream>>>(m, grid, Wp, yi, out, N);
}

// Round 5
// 217.662 us; speedup vs baseline: 1.1212x; 1.0097x over previous
//
#include <hip/hip_runtime.h>

#define KK 49
#define BLK 256
#define PPW 32                 // pixels per wave (TPP=2)
#define PPB 128                // pixels per block (4 waves)
#define WFL (PPW * KK)         // floats per wave slice = 1568
#define WF4 (WFL / 4)          // float4 per wave slice = 392

typedef float v2f __attribute__((ext_vector_type(2)));

static __device__ __forceinline__ v2f v2bc(float s) { v2f r; r.x = s; r.y = s; return r; }

// Catmull-Rom a=-0.5, branchless, packed 2-wide:
// w = 0.5*t2^3 - 0.5*t2^2 + t1^2 - 2*t1^3,  t2=max(0,2-|x|), t1=max(0,1-|x|)
static __device__ __forceinline__ v2f cubic2(v2f x) {
    v2f ax = __builtin_elementwise_abs(x);
    v2f t2 = __builtin_elementwise_max(v2bc(2.0f) - ax, v2bc(0.0f));
    v2f t1 = __builtin_elementwise_max(v2bc(1.0f) - ax, v2bc(0.0f));
    v2f r  = (t2 * t2) * __builtin_elementwise_fma(v2bc(0.5f), t2, v2bc(-0.5f));
    return __builtin_elementwise_fma(t1 * t1,
              __builtin_elementwise_fma(v2bc(-2.0f), t1, v2bc(1.0f)), r);
}

__global__ __launch_bounds__(BLK, 6) void kest_kernel(
    const float* __restrict__ m,
    const float* __restrict__ grid,
    const int*   __restrict__ Wp,
    const int*   __restrict__ yi,
    float*       __restrict__ out,
    int N)
{
    __shared__ __align__(16) float lds[4 * WFL];   // 25088 B -> 6 blocks/CU

    const int tid   = threadIdx.x;
    const int wv_   = tid >> 6;          // wave id 0..3
    const int lane  = tid & 63;
    const int pixW  = lane >> 1;         // pixel-in-wave 0..31
    const int sub   = lane & 1;          // which half of the 49 weights
    const int blockBase = blockIdx.x * PPB;
    float* ldsW = &lds[wv_ * WFL];       // wave-private slice: NO barrier needed

    // ---- setup: lanes 0..31 each compute coeffs for pixel (waveBase+lane) ----
    float Axx = 0.f, Axy = 0.f, Ayx = 0.f, Ayy = 0.f, fxc = 0.f, fyc = 0.f;
    if (lane < 32) {
        const int p = blockBase + wv_ * PPW + lane;
        if (p < N) {
            const float m00 = m[0], m01 = m[1], m02 = m[2];
            const float m10 = m[3], m11 = m[4], m12 = m[5];
            const float m20 = m[6], m21 = m[7], m22 = m[8];
            const int   W   = Wp[0];

            const int j = yi[p];
            int yyI, xxI;
            if ((W & (W - 1)) == 0) {            // uniform branch (W=1024)
                yyI = j >> (__ffs(W) - 1);
                xxI = j & (W - 1);
            } else {
                yyI = j / W;
                xxI = j - yyI * W;
            }
            const float xx = (float)xxI, yy = (float)yyI;

            const float X0 = m00 * xx + m01 * yy + m02;
            const float Y0 = m10 * xx + m11 * yy + m12;
            const float Z0 = m20 * xx + m21 * yy + m22;

            // stable difference-of-quotients: du (eps_y=±0.5), dv (eps_x=±0.5)
            const float izy = __builtin_amdgcn_rcpf(Z0 * Z0 - 0.25f * m21 * m21);
            float du0 = (m01 * Z0 - m21 * X0) * izy;
            float du1 = (m11 * Z0 - m21 * Y0) * izy;
            const float izx = __builtin_amdgcn_rcpf(Z0 * Z0 - 0.25f * m20 * m20);
            float dv0 = (m00 * Z0 - m20 * X0) * izx;
            float dv1 = (m10 * Z0 - m20 * Y0) * izx;

            const float d2u = du0 * du0 + du1 * du1;
            const float rlu = __builtin_amdgcn_rsqf(d2u);
            float len_du = d2u * rlu;
            if (len_du < 1.0f) { du0 *= rlu; du1 *= rlu; len_du = 1.0f; }
            const float d2v = dv0 * dv0 + dv1 * dv1;
            const float rlv = __builtin_amdgcn_rsqf(d2v);
            float len_dv = d2v * rlv;
            if (len_dv < 1.0f) { dv0 *= rlv; dv1 *= rlv; len_dv = 1.0f; }

            const float det  = du0 * dv1 - du1 * dv0;
            const float r_du = __builtin_amdgcn_rcpf(len_du * det);
            const float r_dv = __builtin_amdgcn_rcpf(len_dv * det);

            const float p1 = du0 * dv1, p2 = du1 * dv0;
            Axx = p1 * r_du - p2 * r_dv;
            Axy = du0 * du1 * (r_dv - r_du);
            Ayx = dv0 * dv1 * (r_du - r_dv);
            Ayy = p1 * r_dv - p2 * r_du;

            const float px = grid[p]     + 0.5f;
            const float py = grid[N + p] + 0.5f;
            fxc = (px - __builtin_floorf(px)) + 2.5f;
            fyc = (py - __builtin_floorf(py)) + 2.5f;
        }
    }
    // distribute coeffs: lane needs values from setup-lane pixW (0..31)
    Axx = __shfl(Axx, pixW); Axy = __shfl(Axy, pixW);
    Ayx = __shfl(Ayx, pixW); Ayy = __shfl(Ayy, pixW);
    fxc = __shfl(fxc, pixW); fyc = __shfl(fyc, pixW);

    const int i = blockBase + wv_ * PPW + pixW;   // this lane's pixel
    if (i < N) {
        const float subf = (float)sub;
        const v2f subf2 = v2bc(subf);
        const v2f Axx2 = v2bc(Axx), Axy2 = v2bc(Axy);
        const v2f Ayx2 = v2bc(Ayx), Ayy2 = v2bc(Ayy);

        // weights q = 4j + 2e + sub  (e = vector half), j = 0..12
        v2f wv2[13];
        v2f ws2 = v2bc(0.0f);
#pragma unroll
        for (int j = 0; j < 13; ++j) {
            const int q0 = 4 * j, q1 = 4 * j + 2;
            const float cx0 = (float)(q0 % 7), cx1 = (float)(q1 % 7);
            const float dx0 = (float)((q0 + 1) % 7 - q0 % 7);
            const float dx1 = (float)((q1 + 1) % 7 - q1 % 7);
            const float ry0 = (float)(q0 / 7), ry1 = (float)(q1 / 7);
            const float dy0 = (float)((q0 + 1) / 7 - q0 / 7);
            const float dy1 = (float)((q1 + 1) / 7 - q1 / 7);

            v2f wxv; wxv.x = fxc - cx0; wxv.y = fxc - cx1;
            v2f dxv; dxv.x = -dx0;      dxv.y = -dx1;
            wxv = __builtin_elementwise_fma(subf2, dxv, wxv);
            v2f wyv; wyv.x = fyc - ry0; wyv.y = fyc - ry1;
            v2f dyv; dyv.x = -dy0;      dyv.y = -dy1;
            wyv = __builtin_elementwise_fma(subf2, dyv, wyv);

            v2f x2 = __builtin_elementwise_fma(Axx2, wxv, Axy2 * wyv);
            v2f y2 = __builtin_elementwise_fma(Ayx2, wxv, Ayy2 * wyv);
            v2f w2 = cubic2(x2) * cubic2(y2);
            if (j == 12) {                 // q = 48+sub / 50+sub: mask invalid
                w2.x *= (1.0f - subf);
                w2.y  = 0.0f;
            }
            ws2 += w2;
            wv2[j] = w2;
        }
        float wsum = ws2.x + ws2.y;
        wsum += __shfl_xor(wsum, 1);       // combine the pixel's two lanes
        const float rs = __builtin_amdgcn_rcpf(wsum);
        const v2f rs2 = v2bc(rs);

        // LDS write: addr = pixW*49 + 4j + 2e + sub; banks 17*pixW+sub mod 32
        // -> at most 2-way aliasing (free)
        float* base = &ldsW[pixW * KK + sub];
#pragma unroll
        for (int j = 0; j < 13; ++j) {
            const v2f v = wv2[j] * rs2;
            if (j < 12) {
                base[4 * j]     = v.x;
                base[4 * j + 2] = v.y;
            } else if (sub == 0) {
                base[48] = v.x;            // q=48 only; q>=49 would corrupt
            }
        }
    }

    // ---- wave-private drain, no barrier: compiler's lgkmcnt wait suffices ----
    const long long dstF4 = (long long)blockIdx.x * (PPB * KK / 4) + wv_ * WF4;
    if (blockBase + PPB <= N) {            // uniform fast path: block fully valid
        const float4* src = (const float4*)ldsW;
        float4* dst = (float4*)out + dstF4;
#pragma unroll
        for (int k = 0; k < 7; ++k) {
            const int t = lane + 64 * k;
            if (t < WF4) dst[t] = src[t];  // k<6 always; k=6: lanes 0..7
        }
    } else {                               // tail block: scalar, bounds-checked
        const float* s = (const float*)ldsW;
        const long long baseF = dstF4 * 4;
        const long long limF  = (long long)N * KK;
        for (int t = lane; t < WFL; t += 64)
            if (baseF + t < limF) out[baseF + t] = s[t];
    }
}

extern "C" void kernel_launch(void* const* d_in, const int* in_sizes, int n_in,
                              void* d_out, int out_size, void* d_ws, size_t ws_size,
                              hipStream_t stream) {
    // inputs: m_inverse(9 f32), grid(2N f32), H(1 i32), W(1 i32), yi(N i32)
    const float* m    = (const float*)d_in[0];
    const float* grid = (const float*)d_in[1];
    const int*   Wp   = (const int*)d_in[3];
    const int*   yi   = (const int*)d_in[4];
    float*       out  = (float*)d_out;
    const int N = in_sizes[4];

    const int blocks = (N + PPB - 1) / PPB;
    kest_kernel<<<blocks, BLK, 0, stream>>>(m, grid, Wp, yi, out, N);
}